// Round 9
// baseline (38.432 us; speedup 1.0000x reference)
//
#include <hip/hip_runtime.h>

// Problem constants from the reference (B=4, N=1024, D=256).
#define B_DIM 4
#define N_DIM 1024
#define D_DIM 256             // ej < 256 always (nonzero over last dim of x)
#define NROWS (B_DIM * N_DIM) // 4096
#define ITILE 8               // i-rows per block in gram kernel
#define NBLK_G (NROWS / ITILE)// 512
#define REPEAT 4              // ATTRIBUTION PROBE: edge kernel repeats its
                              // (idempotent) work 4x; dur encodes its cost.

typedef __bf16 bf16x8 __attribute__((ext_vector_type(8)));
typedef float  f32x4  __attribute__((ext_vector_type(4)));

// ---- Kernel 1: MFMA Gram tile -> Dtab[b][i][j] = ||x_i - x_j|| ------------
// Reads f32 x directly (L2-resident), converts inline, accumulates exact f32
// norms alongside. 512 blocks x 512 threads (8 waves). Block owns 8 i-rows x
// 256 j; wave w owns j in [32w, 32w+32) via 2 fragments.
__global__ __launch_bounds__(512) void gram_dtab_kernel(
    const float* __restrict__ x, float* __restrict__ Dtab)
{
    const int bid = (int)blockIdx.x;     // 0..511
    const int r0  = bid * ITILE;         // flat row = b*1024 + i
    const int b   = r0 >> 10;
    const int i0  = r0 & (N_DIM - 1);
    const float* __restrict__ Xb = x + (size_t)b * N_DIM * D_DIM;

    const int tid  = (int)threadIdx.x;
    const int lane = tid & 63;
    const int wid  = tid >> 6;           // 0..7
    const int jbase = wid * 32;
    const int rsel = lane & 15;
    const int kg   = lane >> 4;          // k-group 0..3

    const float* ap  = Xb + (size_t)(i0 + (rsel & (ITILE - 1))) * D_DIM + kg * 8;
    const float* bp0 = Xb + (size_t)(jbase + rsel) * D_DIM + kg * 8;
    const float* bp1 = Xb + (size_t)(jbase + 16 + rsel) * D_DIM + kg * 8;

    f32x4 acc[2] = {};
    float na = 0.f, nb0 = 0.f, nb1 = 0.f;

    #pragma unroll
    for (int k0 = 0; k0 < D_DIM; k0 += 32) {
        float4 a0 = *(const float4*)(ap + k0);
        float4 a1 = *(const float4*)(ap + k0 + 4);
        float4 c0 = *(const float4*)(bp0 + k0);
        float4 c1 = *(const float4*)(bp0 + k0 + 4);
        float4 e0 = *(const float4*)(bp1 + k0);
        float4 e1 = *(const float4*)(bp1 + k0 + 4);
        bf16x8 af, bf0, bf1;
        af[0]=(__bf16)a0.x; af[1]=(__bf16)a0.y; af[2]=(__bf16)a0.z; af[3]=(__bf16)a0.w;
        af[4]=(__bf16)a1.x; af[5]=(__bf16)a1.y; af[6]=(__bf16)a1.z; af[7]=(__bf16)a1.w;
        bf0[0]=(__bf16)c0.x; bf0[1]=(__bf16)c0.y; bf0[2]=(__bf16)c0.z; bf0[3]=(__bf16)c0.w;
        bf0[4]=(__bf16)c1.x; bf0[5]=(__bf16)c1.y; bf0[6]=(__bf16)c1.z; bf0[7]=(__bf16)c1.w;
        bf1[0]=(__bf16)e0.x; bf1[1]=(__bf16)e0.y; bf1[2]=(__bf16)e0.z; bf1[3]=(__bf16)e0.w;
        bf1[4]=(__bf16)e1.x; bf1[5]=(__bf16)e1.y; bf1[6]=(__bf16)e1.z; bf1[7]=(__bf16)e1.w;
        na  += a0.x*a0.x + a0.y*a0.y + a0.z*a0.z + a0.w*a0.w
             + a1.x*a1.x + a1.y*a1.y + a1.z*a1.z + a1.w*a1.w;
        nb0 += c0.x*c0.x + c0.y*c0.y + c0.z*c0.z + c0.w*c0.w
             + c1.x*c1.x + c1.y*c1.y + c1.z*c1.z + c1.w*c1.w;
        nb1 += e0.x*e0.x + e0.y*e0.y + e0.z*e0.z + e0.w*e0.w
             + e1.x*e1.x + e1.y*e1.y + e1.z*e1.z + e1.w*e1.w;
        acc[0] = __builtin_amdgcn_mfma_f32_16x16x32_bf16(af, bf0, acc[0], 0, 0, 0);
        acc[1] = __builtin_amdgcn_mfma_f32_16x16x32_bf16(af, bf1, acc[1], 0, 0, 0);
    }

    // Reduce norms over the 4 k-groups (lanes sharing lane&15).
    na  += __shfl_xor(na, 16, 64);  na  += __shfl_xor(na, 32, 64);
    nb0 += __shfl_xor(nb0, 16, 64); nb0 += __shfl_xor(nb0, 32, 64);
    nb1 += __shfl_xor(nb1, 16, 64); nb1 += __shfl_xor(nb1, 32, 64);

    // Epilogue: C/D layout col=lane&15, row=(lane>>4)*4+r (m89-verified).
    // This lane's nb0/nb1 are exactly the norms of its output columns.
    #pragma unroll
    for (int f = 0; f < 2; ++f) {
        const int col  = jbase + f * 16 + rsel;
        const float nj = (f == 0) ? nb0 : nb1;
        #pragma unroll
        for (int r = 0; r < 4; ++r) {
            const int rloc = kg * 4 + r;
            if (rloc < ITILE) {
                const float ni = __shfl(na, rloc, 64);   // lane rloc holds row i0+rloc
                float d2 = ni + nj - 2.0f * acc[f][r];
                float d  = sqrtf(fmaxf(d2, 0.0f));
                if (i0 + rloc == col) d = 0.0f;          // exact zero on diagonal
                Dtab[((size_t)(r0 + rloc)) * D_DIM + col] = d;
            }
        }
    }
}

// ---- Kernel 2: edge gather, full occupancy, REPEATed for attribution ------
// 2 threads per edge; each writes one float4 (16 B, coalesced). The REPEAT
// loop re-does identical (idempotent, deterministic) work; the asm memory
// clobber prevents load-CSE / dead-store elimination across iterations.
__global__ __launch_bounds__(256) void edge_out_kernel(
    const int* __restrict__ eb, const int* __restrict__ ei,
    const int* __restrict__ ej, const float* __restrict__ Dtab,
    float* out, int E)
{
    const int t = (int)blockIdx.x * 256 + (int)threadIdx.x;
    const int e = t >> 1;
    if (e >= E) return;
    #pragma unroll 1
    for (int rep = 0; rep < REPEAT; ++rep) {
        const float d = Dtab[((size_t)eb[e] * N_DIM + ei[e]) * D_DIM + ej[e]];
        *(float4*)(out + (size_t)e * 8 + (t & 1) * 4) = make_float4(d, d, d, d);
        asm volatile("" ::: "memory");
    }
}

// ---- Fallback (ws too small): direct per-edge wave ------------------------
__global__ __launch_bounds__(256) void edge_dist_direct_kernel(
    const float* __restrict__ x,
    const int* __restrict__ eb, const int* __restrict__ ei,
    const int* __restrict__ ej, float* __restrict__ out, int E)
{
    const int wave = (int)((blockIdx.x * (unsigned)blockDim.x + threadIdx.x) >> 6);
    if (wave >= E) return;
    const int lane = (int)(threadIdx.x & 63u);
    const int b = eb[wave], i = ei[wave], j = ej[wave];
    const float4 a = reinterpret_cast<const float4*>(x + ((size_t)b * N_DIM + i) * D_DIM)[lane];
    const float4 c = reinterpret_cast<const float4*>(x + ((size_t)b * N_DIM + j) * D_DIM)[lane];
    const float dx = a.x - c.x, dy = a.y - c.y, dz = a.z - c.z, dw = a.w - c.w;
    float s = dx * dx + dy * dy + dz * dz + dw * dw;
    #pragma unroll
    for (int off = 32; off >= 1; off >>= 1) s += __shfl_xor(s, off, 64);
    const float d = sqrtf(s);
    if (lane < 2)
        reinterpret_cast<float4*>(out + (size_t)wave * 8)[lane] =
            make_float4(d, d, d, d);
}

extern "C" void kernel_launch(void* const* d_in, const int* in_sizes, int n_in,
                              void* d_out, int out_size, void* d_ws, size_t ws_size,
                              hipStream_t stream) {
    const float* x  = (const float*)d_in[0];
    const int*   eb = (const int*)d_in[1];
    const int*   ei = (const int*)d_in[2];
    const int*   ej = (const int*)d_in[3];
    float* out = (float*)d_out;
    const int E = in_sizes[1];
    if (E <= 0) return;

    const size_t dtab_bytes = (size_t)NROWS * D_DIM * sizeof(float);  // 4 MB

    if (ws_size >= dtab_bytes) {
        float* Dtab = (float*)d_ws;
        gram_dtab_kernel<<<NBLK_G, 512, 0, stream>>>(x, Dtab);
        const int threads = 2 * E;
        edge_out_kernel<<<(threads + 255) / 256, 256, 0, stream>>>(eb, ei, ej, Dtab, out, E);
    } else {
        const int blocks = (E + 3) / 4;  // 4 waves/block
        edge_dist_direct_kernel<<<blocks, 256, 0, stream>>>(x, eb, ei, ej, out, E);
    }
}

// Round 10
// 28.684 us; speedup vs baseline: 1.3398x; 1.3398x over previous
//
#include <hip/hip_runtime.h>

// Problem constants from the reference (B=4, N=1024, D=256).
#define B_DIM 4
#define N_DIM 1024
#define D_DIM 256             // ej < 256 always (nonzero over last dim of x)
#define NROWS (B_DIM * N_DIM) // 4096
#define LDT 264               // LDS tile row stride in bf16 (256 + 8 pad)

typedef __bf16 bf16x8 __attribute__((ext_vector_type(8)));
typedef __bf16 bf16x4 __attribute__((ext_vector_type(4)));
typedef float  f32x4  __attribute__((ext_vector_type(4)));

// ---- Kernel 1: LDS-tiled MFMA Gram -> Dtab[b][i][j] = ||x_i - x_j|| -------
// Canonical GEMM anatomy: coalesced global->LDS staging (f32->bf16 convert in
// regs), fragments via ds_read_b128, K=256 fully resident (no k-staging loop).
// Block = 256 thr (4 waves, 2x2), tile 64(i) x 64(j). Grid (4, 16, 4) = 256.
// Exact f32 row norms computed during staging (wave holds one full row/rep).
__global__ __launch_bounds__(256) void gram_dtab_kernel(
    const float* __restrict__ x, float* __restrict__ Dtab)
{
    const int j0 = (int)blockIdx.x * 64;   // 0..192
    const int i0 = (int)blockIdx.y * 64;   // 0..960
    const int b  = (int)blockIdx.z;
    const float* __restrict__ Xb = x + (size_t)b * N_DIM * D_DIM;

    __shared__ __bf16 Asl[64 * LDT];
    __shared__ __bf16 Bsl[64 * LDT];
    __shared__ float  na_lds[64];
    __shared__ float  nb_lds[64];

    const int t  = (int)threadIdx.x;
    const int w  = t >> 6;                 // wave 0..3
    const int lq = t & 63;                 // lane

    // --- Staging: per rep, wave w's 64 lanes hold one full row (64 float4).
    #pragma unroll
    for (int rep = 0; rep < 16; ++rep) {
        const int row = rep * 4 + w;       // 0..63
        const float4 v = *(const float4*)(Xb + (size_t)(i0 + row) * D_DIM + lq * 4);
        bf16x4 h;
        h[0] = (__bf16)v.x; h[1] = (__bf16)v.y; h[2] = (__bf16)v.z; h[3] = (__bf16)v.w;
        *(bf16x4*)&Asl[row * LDT + lq * 4] = h;
        float s = v.x*v.x + v.y*v.y + v.z*v.z + v.w*v.w;
        #pragma unroll
        for (int off = 32; off >= 1; off >>= 1) s += __shfl_xor(s, off, 64);
        if (lq == 0) na_lds[row] = s;
    }
    #pragma unroll
    for (int rep = 0; rep < 16; ++rep) {
        const int row = rep * 4 + w;
        const float4 v = *(const float4*)(Xb + (size_t)(j0 + row) * D_DIM + lq * 4);
        bf16x4 h;
        h[0] = (__bf16)v.x; h[1] = (__bf16)v.y; h[2] = (__bf16)v.z; h[3] = (__bf16)v.w;
        *(bf16x4*)&Bsl[row * LDT + lq * 4] = h;
        float s = v.x*v.x + v.y*v.y + v.z*v.z + v.w*v.w;
        #pragma unroll
        for (int off = 32; off >= 1; off >>= 1) s += __shfl_xor(s, off, 64);
        if (lq == 0) nb_lds[row] = s;
    }
    __syncthreads();

    // --- MFMA from LDS: wave (wm,wn) owns a 32x32 sub-tile, 2x2 fragments.
    const int lane = t & 63;
    const int wm   = w >> 1, wn = w & 1;
    const int rsel = lane & 15;
    const int kg   = lane >> 4;            // k-group 0..3

    f32x4 acc[2][2] = {};
    #pragma unroll
    for (int k0 = 0; k0 < D_DIM; k0 += 32) {
        const bf16x8 a0 = *(const bf16x8*)&Asl[(wm*32 +      rsel) * LDT + k0 + kg*8];
        const bf16x8 a1 = *(const bf16x8*)&Asl[(wm*32 + 16 + rsel) * LDT + k0 + kg*8];
        const bf16x8 b0 = *(const bf16x8*)&Bsl[(wn*32 +      rsel) * LDT + k0 + kg*8];
        const bf16x8 b1 = *(const bf16x8*)&Bsl[(wn*32 + 16 + rsel) * LDT + k0 + kg*8];
        acc[0][0] = __builtin_amdgcn_mfma_f32_16x16x32_bf16(a0, b0, acc[0][0], 0, 0, 0);
        acc[0][1] = __builtin_amdgcn_mfma_f32_16x16x32_bf16(a0, b1, acc[0][1], 0, 0, 0);
        acc[1][0] = __builtin_amdgcn_mfma_f32_16x16x32_bf16(a1, b0, acc[1][0], 0, 0, 0);
        acc[1][1] = __builtin_amdgcn_mfma_f32_16x16x32_bf16(a1, b1, acc[1][1], 0, 0, 0);
    }

    // --- Epilogue: C/D layout col=lane&15, row=(lane>>4)*4+r (m89-verified).
    #pragma unroll
    for (int fm = 0; fm < 2; ++fm) {
        #pragma unroll
        for (int fn = 0; fn < 2; ++fn) {
            const int ccol = wn*32 + fn*16 + rsel;          // local j
            const float nj = nb_lds[ccol];
            #pragma unroll
            for (int r = 0; r < 4; ++r) {
                const int crow = wm*32 + fm*16 + kg*4 + r;  // local i
                const float ni = na_lds[crow];
                float d2 = ni + nj - 2.0f * acc[fm][fn][r];
                float d  = sqrtf(fmaxf(d2, 0.0f));
                if (i0 + crow == j0 + ccol) d = 0.0f;       // exact zero on diag
                Dtab[((size_t)b * N_DIM + i0 + crow) * D_DIM + (j0 + ccol)] = d;
            }
        }
    }
}

// ---- Kernel 2: edge gather, full occupancy (measured ~4.3 us, at floor) ---
// 2 threads per edge; each writes one float4 (16 B, coalesced).
__global__ __launch_bounds__(256) void edge_out_kernel(
    const int* __restrict__ eb, const int* __restrict__ ei,
    const int* __restrict__ ej, const float* __restrict__ Dtab,
    float* __restrict__ out, int E)
{
    const int t = (int)blockIdx.x * 256 + (int)threadIdx.x;
    const int e = t >> 1;
    if (e >= E) return;
    const float d = Dtab[((size_t)eb[e] * N_DIM + ei[e]) * D_DIM + ej[e]];
    *(float4*)(out + (size_t)e * 8 + (t & 1) * 4) = make_float4(d, d, d, d);
}

// ---- Fallback (ws too small): direct per-edge wave ------------------------
__global__ __launch_bounds__(256) void edge_dist_direct_kernel(
    const float* __restrict__ x,
    const int* __restrict__ eb, const int* __restrict__ ei,
    const int* __restrict__ ej, float* __restrict__ out, int E)
{
    const int wave = (int)((blockIdx.x * (unsigned)blockDim.x + threadIdx.x) >> 6);
    if (wave >= E) return;
    const int lane = (int)(threadIdx.x & 63u);
    const int b = eb[wave], i = ei[wave], j = ej[wave];
    const float4 a = reinterpret_cast<const float4*>(x + ((size_t)b * N_DIM + i) * D_DIM)[lane];
    const float4 c = reinterpret_cast<const float4*>(x + ((size_t)b * N_DIM + j) * D_DIM)[lane];
    const float dx = a.x - c.x, dy = a.y - c.y, dz = a.z - c.z, dw = a.w - c.w;
    float s = dx * dx + dy * dy + dz * dz + dw * dw;
    #pragma unroll
    for (int off = 32; off >= 1; off >>= 1) s += __shfl_xor(s, off, 64);
    const float d = sqrtf(s);
    if (lane < 2)
        reinterpret_cast<float4*>(out + (size_t)wave * 8)[lane] =
            make_float4(d, d, d, d);
}

extern "C" void kernel_launch(void* const* d_in, const int* in_sizes, int n_in,
                              void* d_out, int out_size, void* d_ws, size_t ws_size,
                              hipStream_t stream) {
    const float* x  = (const float*)d_in[0];
    const int*   eb = (const int*)d_in[1];
    const int*   ei = (const int*)d_in[2];
    const int*   ej = (const int*)d_in[3];
    float* out = (float*)d_out;
    const int E = in_sizes[1];
    if (E <= 0) return;

    const size_t dtab_bytes = (size_t)NROWS * D_DIM * sizeof(float);  // 4 MB

    if (ws_size >= dtab_bytes) {
        float* Dtab = (float*)d_ws;
        dim3 ggrid(D_DIM / 64, N_DIM / 64, B_DIM);   // (4, 16, 4) = 256 blocks
        gram_dtab_kernel<<<ggrid, 256, 0, stream>>>(x, Dtab);
        const int threads = 2 * E;
        edge_out_kernel<<<(threads + 255) / 256, 256, 0, stream>>>(eb, ei, ej, Dtab, out, E);
    } else {
        const int blocks = (E + 3) / 4;  // 4 waves/block
        edge_dist_direct_kernel<<<blocks, 256, 0, stream>>>(x, eb, ei, ej, out, E);
    }
}